// Round 9
// baseline (197.657 us; speedup 1.0000x reference)
//
#include <hip/hip_runtime.h>
#include <hip/hip_bf16.h>

// EdgeNetwork R8b: R7 structure (transposed-GEMM, K-permuted weights, hidden
// state in registers, pk-f32 epilogue) + occupancy & transcendental trims:
//  - params (g/q/w3/b) read from global pp (L1-hot) instead of LDS -> LDS
//    exactly 32768 B; __launch_bounds__(256,5) -> 5 blocks/CU, 20 waves/CU.
//  - 2*log2e folded into gamma/beta at prep: tanh = 1-2*rcp(2^z+1) via raw
//    v_exp_f32 (inline asm; __exp2f does not exist in HIP device code).
// Tripwire: WRITE_SIZE >> 2.3 MB => (256,5) spilled -> revert to (256,4).

typedef float f32x2 __attribute__((ext_vector_type(2)));
typedef float f32x4 __attribute__((ext_vector_type(4)));
typedef __bf16 bf16x8 __attribute__((ext_vector_type(8)));
typedef unsigned int u32x4 __attribute__((ext_vector_type(4)));

#define MFMA16(a, b, c) __builtin_amdgcn_mfma_f32_16x16x32_bf16((a), (b), (c), 0, 0, 0)
#define TWO_LOG2E 2.885390081777927f

static __device__ __forceinline__ unsigned short bf16bits(float f) {
  __bf16 h = (__bf16)f;
  return __builtin_bit_cast(unsigned short, h);
}

static __device__ __forceinline__ unsigned pack2(float a, float b) {
  return (unsigned)bf16bits(a) | ((unsigned)bf16bits(b) << 16);
}

static __device__ __forceinline__ float exp2_fast(float z) {
  float r;
  asm("v_exp_f32 %0, %1" : "=v"(r) : "v"(z));
  return r;  // 2^z, v_exp_f32 semantics
}

static __device__ __forceinline__ void gload_lds16(const void* g, void* l) {
  __builtin_amdgcn_global_load_lds(
      (const __attribute__((address_space(1))) void*)g,
      (__attribute__((address_space(3))) void*)l, 16, 0, 0);
}

// K-row permutation for layer>=1 weights (within each 32-row block):
// k = blk + g*8 + j  ->  blk + (j>>2)*16 + g*4 + (j&3)
static __device__ __forceinline__ int permk(int k) {
  const int j = k & 7, g = (k >> 3) & 3;
  return (k & ~31) | ((j >> 2) << 4) | (g << 2) | (j & 3);
}

// ---- prep: x (f32) -> xb (bf16) ----
__global__ void prep_x(const float* __restrict__ x,
                       unsigned short* __restrict__ xb, int n8) {
  int gid = blockIdx.x * blockDim.x + threadIdx.x;
  const int stride = gridDim.x * blockDim.x;
  for (int i = gid; i < n8; i += stride) {
    const float4 a = ((const float4*)x)[i * 2];
    const float4 b = ((const float4*)x)[i * 2 + 1];
    u32x4 o;
    o[0] = pack2(a.x, a.y); o[1] = pack2(a.z, a.w);
    o[2] = pack2(b.x, b.y); o[3] = pack2(b.z, b.w);
    ((u32x4*)xb)[i] = o;
  }
}

// ---- prep: weight slabs (swizzled, K-permuted for W1/W2) + param block ----
// pp[1280] = B0, G0*, Q0*, B1, G1*, Q1*, B2, G2*, Q2*, W3 (128 f32 each);
// * entries pre-scaled by 2*log2(e) for the exp2-form tanh.
__global__ void prep_w(const float* __restrict__ W0, const float* __restrict__ W1,
                       const float* __restrict__ W2,
                       const float* __restrict__ B0, const float* __restrict__ G0,
                       const float* __restrict__ Q0,
                       const float* __restrict__ B1, const float* __restrict__ G1,
                       const float* __restrict__ Q1,
                       const float* __restrict__ B2, const float* __restrict__ G2,
                       const float* __restrict__ Q2,
                       const float* __restrict__ W3,
                       unsigned short* __restrict__ wt, float* __restrict__ pp) {
  const int t = blockIdx.x;
  const int tid = threadIdx.x;
  if (t == 8) {
    for (int i = tid; i < 1280; i += 256) {
      const int a = i >> 7, o = i & 127;
      float v;
      switch (a) {
        case 0: v = B0[o]; break;
        case 1: v = G0[o] * TWO_LOG2E; break;
        case 2: v = Q0[o] * TWO_LOG2E; break;
        case 3: v = B1[o]; break;
        case 4: v = G1[o] * TWO_LOG2E; break;
        case 5: v = Q1[o] * TWO_LOG2E; break;
        case 6: v = B2[o]; break;
        case 7: v = G2[o] * TWO_LOG2E; break;
        case 8: v = Q2[o] * TWO_LOG2E; break;
        default: v = W3[o]; break;
      }
      pp[i] = v;
    }
    return;
  }
  const float* src; int kbase; int perm;
  if (t < 4)      { src = W0; kbase = t * 64;      perm = 0; }
  else if (t < 6) { src = W1; kbase = (t - 4) * 64; perm = 1; }
  else            { src = W2; kbase = (t - 6) * 64; perm = 1; }
  char* base = (char*)wt + t * 16384;
  const int col = tid & 127;
  const int kb  = (tid >> 7) << 1;
  #pragma unroll
  for (int i = 0; i < 16; ++i) {
    const int kl = kb + (i << 2);
    const int k0 = kbase + kl;
    const int c0 = perm ? permk(k0) : k0;  // c(k0+1) == c0+1 (k0 even)
    const float wa = src[c0 * 128 + col];
    const float wb = src[(c0 + 1) * 128 + col];
    const unsigned pk = pack2(wa, wb);
    const int off = ((col * 64 + kl) * 2) ^ ((col & 7) << 4);
    *(unsigned*)(base + off) = pk;
  }
}

#define P_B0 0
#define P_G0 128
#define P_Q0 256
#define P_B1 384
#define P_G1 512
#define P_Q1 640
#define P_B2 768
#define P_G2 896
#define P_Q2 1024
#define P_W3 1152

template <int XB>
__global__ __launch_bounds__(256, 5) void edge_mlp(
    const float* __restrict__ x, const int* __restrict__ ei,
    const float* __restrict__ B3,
    const unsigned short* __restrict__ wt, const float* __restrict__ pp,
    const unsigned short* __restrict__ xb,
    float* __restrict__ out, int nE)
{
  __shared__ __align__(16) char lds[32768];
  const int tid  = threadIdx.x;
  const int lane = tid & 63;
  const int wv   = tid >> 6;
  const int e    = lane & 15;  // edge within tile (N dim)
  const int g    = lane >> 4;  // k-group / accumulator row group

  const int wbase = blockIdx.x * 64 + wv * 16;   // 16 edges per wave
  const int e0 = wbase + e;
  const int ec0 = e0 < nE ? e0 : nE - 1;
  const int ns0 = ei[ec0], ne0 = ei[nE + ec0];

  auto stageW = [&](int t, int buf) {
    #pragma unroll
    for (int c = 0; c < 4; ++c) {
      const int o = wv * 4096 + c * 1024;
      gload_lds16((const char*)wt + t * 16384 + o + lane * 16,
                  lds + buf * 16384 + o);
    }
  };

  auto loadW = [&](int buf, int m, int kl) -> bf16x8 {
    const int col = m * 16 + e;
    const int off = ((col * 64 + kl) * 2) ^ ((col & 7) << 4);
    return *(const bf16x8*)(lds + buf * 16384 + off);
  };

  auto loadX = [&](int node, int ko) -> bf16x8 {
    if (XB) {
      return *(const bf16x8*)(xb + (size_t)node * 128 + ko);
    } else {
      const float* src = x + (size_t)node * 128 + ko;
      const float4 ua = *(const float4*)(src);
      const float4 ub = *(const float4*)(src + 4);
      bf16x8 a;
      a[0] = (__bf16)ua.x; a[1] = (__bf16)ua.y; a[2] = (__bf16)ua.z; a[3] = (__bf16)ua.w;
      a[4] = (__bf16)ub.x; a[5] = (__bf16)ub.y; a[6] = (__bf16)ub.z; a[7] = (__bf16)ub.w;
      return a;
    }
  };

  f32x4 acc[8];

  auto initAcc = [&](int pb) {
    #pragma unroll
    for (int m = 0; m < 8; ++m)
      acc[m] = *(const f32x4*)(pp + pb + m * 16 + g * 4);
  };

  auto l0step = [&](int u0, int buf) {
    #pragma unroll
    for (int du = 0; du < 2; ++du) {
      const int u = u0 + du;
      const int ko = (u & 3) * 32 + g * 8;
      const bf16x8 xf = loadX(u < 4 ? ns0 : ne0, ko);
      const int kl = du * 32 + g * 8;
      #pragma unroll
      for (int m = 0; m < 8; ++m) {
        const bf16x8 wf = loadW(buf, m, kl);
        acc[m] = MFMA16(wf, xf, acc[m]);
      }
    }
  };

  unsigned p0[8], p1[8];

  // LN + tanh + pack; params pre-scaled by 2*log2e -> tanh = 1-2/(2^z+1).
  auto epi = [&](int pg, int pq) {
    f32x2 s1 = {0.f, 0.f}, s2 = {0.f, 0.f};
    #pragma unroll
    for (int m = 0; m < 8; ++m) {
      const f32x2 lo = {acc[m][0], acc[m][1]};
      const f32x2 hi = {acc[m][2], acc[m][3]};
      s1 += lo; s1 += hi;
      s2 = __builtin_elementwise_fma(lo, lo, s2);
      s2 = __builtin_elementwise_fma(hi, hi, s2);
    }
    float sh1 = s1[0] + s1[1], sh2 = s2[0] + s2[1];
    sh1 += __shfl_xor(sh1, 16); sh2 += __shfl_xor(sh2, 16);
    sh1 += __shfl_xor(sh1, 32); sh2 += __shfl_xor(sh2, 32);
    const float mu  = sh1 * 0.0078125f;
    const float inv = __builtin_amdgcn_rsqf(sh2 * 0.0078125f - mu * mu + 1e-5f);
    const f32x2 mu2 = {mu, mu}, inv2 = {inv, inv};
    const f32x2 one2 = {1.f, 1.f}, negtwo2 = {-2.f, -2.f};
    #pragma unroll
    for (int m = 0; m < 8; ++m) {
      const f32x4 gq4 = *(const f32x4*)(pp + pg + m * 16 + g * 4);
      const f32x4 qq4 = *(const f32x4*)(pp + pq + m * 16 + g * 4);
      #pragma unroll
      for (int h = 0; h < 2; ++h) {
        const f32x2 a  = {acc[m][2 * h], acc[m][2 * h + 1]};
        const f32x2 gq = {gq4[2 * h], gq4[2 * h + 1]};
        const f32x2 qq = {qq4[2 * h], qq4[2 * h + 1]};
        const f32x2 k1 = inv2 * gq;
        const f32x2 z  = __builtin_elementwise_fma(a - mu2, k1, qq);
        const f32x2 ex  = {exp2_fast(z[0]), exp2_fast(z[1])};
        const f32x2 den = ex + one2;
        const f32x2 rc  = {__builtin_amdgcn_rcpf(den[0]),
                           __builtin_amdgcn_rcpf(den[1])};
        const f32x2 th  = __builtin_elementwise_fma(negtwo2, rc, one2);
        if (h == 0) p0[m] = pack2(th[0], th[1]);
        else        p1[m] = pack2(th[0], th[1]);
      }
    }
  };

  auto lstep = [&](int u0, int buf) {
    #pragma unroll
    for (int du = 0; du < 2; ++du) {
      const int u = u0 + du;
      const int kl = du * 32 + g * 8;
      u32x4 w;
      w[0] = p0[2 * u];     w[1] = p1[2 * u];
      w[2] = p0[2 * u + 1]; w[3] = p1[2 * u + 1];
      const bf16x8 bfv = __builtin_bit_cast(bf16x8, w);
      #pragma unroll
      for (int m = 0; m < 8; ++m) {
        const bf16x8 wf = loadW(buf, m, kl);
        acc[m] = MFMA16(wf, bfv, acc[m]);
      }
    }
  };

  // ---------------- schedule (8 barriers, dbuf slabs) ----------------
  stageW(0, 0);
  __syncthreads();

  initAcc(P_B0);
  stageW(1, 1); l0step(0, 0); __syncthreads();
  stageW(2, 0); l0step(2, 1); __syncthreads();
  stageW(3, 1); l0step(4, 0); __syncthreads();
  stageW(4, 0); l0step(6, 1); __syncthreads();            // buf0 <- W1 k0-63
  stageW(5, 1);                                            // buf1 <- W1 k64-127
  epi(P_G0, P_Q0); initAcc(P_B1); lstep(0, 0); __syncthreads();
  stageW(6, 0);                                            // buf0 <- W2 k0-63
  lstep(2, 1); __syncthreads();
  stageW(7, 1);                                            // buf1 <- W2 k64-127
  epi(P_G1, P_Q1); initAcc(P_B2); lstep(0, 0); __syncthreads();
  lstep(2, 1);

  // ---- final: LN + tanh + dot W3 + b3, f32x2-packed, exp2 form ----
  const float b3v = B3[0];
  {
    f32x2 s1 = {0.f, 0.f}, s2 = {0.f, 0.f};
    #pragma unroll
    for (int m = 0; m < 8; ++m) {
      const f32x2 lo = {acc[m][0], acc[m][1]};
      const f32x2 hi = {acc[m][2], acc[m][3]};
      s1 += lo; s1 += hi;
      s2 = __builtin_elementwise_fma(lo, lo, s2);
      s2 = __builtin_elementwise_fma(hi, hi, s2);
    }
    float sh1 = s1[0] + s1[1], sh2 = s2[0] + s2[1];
    sh1 += __shfl_xor(sh1, 16); sh2 += __shfl_xor(sh2, 16);
    sh1 += __shfl_xor(sh1, 32); sh2 += __shfl_xor(sh2, 32);
    const float mu  = sh1 * 0.0078125f;
    const float inv = __builtin_amdgcn_rsqf(sh2 * 0.0078125f - mu * mu + 1e-5f);
    const f32x2 mu2 = {mu, mu}, inv2 = {inv, inv};
    const f32x2 one2 = {1.f, 1.f}, negtwo2 = {-2.f, -2.f};
    f32x2 d2 = {0.f, 0.f};
    #pragma unroll
    for (int m = 0; m < 8; ++m) {
      const f32x4 gq4 = *(const f32x4*)(pp + P_G2 + m * 16 + g * 4);
      const f32x4 qq4 = *(const f32x4*)(pp + P_Q2 + m * 16 + g * 4);
      const f32x4 w34 = *(const f32x4*)(pp + P_W3 + m * 16 + g * 4);
      #pragma unroll
      for (int h = 0; h < 2; ++h) {
        const f32x2 a  = {acc[m][2 * h], acc[m][2 * h + 1]};
        const f32x2 gq = {gq4[2 * h], gq4[2 * h + 1]};
        const f32x2 qq = {qq4[2 * h], qq4[2 * h + 1]};
        const f32x2 w3 = {w34[2 * h], w34[2 * h + 1]};
        const f32x2 k1 = inv2 * gq;
        const f32x2 z  = __builtin_elementwise_fma(a - mu2, k1, qq);
        const f32x2 ex  = {exp2_fast(z[0]), exp2_fast(z[1])};
        const f32x2 den = ex + one2;
        const f32x2 rc  = {__builtin_amdgcn_rcpf(den[0]),
                           __builtin_amdgcn_rcpf(den[1])};
        const f32x2 th  = __builtin_elementwise_fma(negtwo2, rc, one2);
        d2 = __builtin_elementwise_fma(th, w3, d2);
      }
    }
    float d = d2[0] + d2[1];
    d += __shfl_xor(d, 16);
    d += __shfl_xor(d, 32);
    const int eid = wbase + e;
    if (g == 0 && eid < nE) out[eid] = d + b3v;
  }
}

extern "C" void kernel_launch(void* const* d_in, const int* in_sizes, int n_in,
                              void* d_out, int out_size, void* d_ws, size_t ws_size,
                              hipStream_t stream) {
  const float* x  = (const float*)d_in[0];
  const int*   ei = (const int*)d_in[1];
  const float* W0 = (const float*)d_in[2];
  const float* B0 = (const float*)d_in[3];
  const float* W1 = (const float*)d_in[4];
  const float* B1 = (const float*)d_in[5];
  const float* W2 = (const float*)d_in[6];
  const float* B2 = (const float*)d_in[7];
  const float* W3 = (const float*)d_in[8];
  const float* B3 = (const float*)d_in[9];
  const float* G0 = (const float*)d_in[10];
  const float* Q0 = (const float*)d_in[11];
  const float* G1 = (const float*)d_in[12];
  const float* Q1 = (const float*)d_in[13];
  const float* G2 = (const float*)d_in[14];
  const float* Q2 = (const float*)d_in[15];
  float* out = (float*)d_out;

  const int nX = in_sizes[0];
  const int nE = in_sizes[1] / 2;
  const int blocks = (nE + 63) / 64;

  const size_t xb_bytes = ((size_t)nX * 2 + 255) & ~(size_t)255;
  const int use_xb = (ws_size >= xb_bytes + 131072 + 5120) ? 1 : 0;

  unsigned short* xbp = (unsigned short*)d_ws;
  unsigned short* wt  = use_xb ? (unsigned short*)((char*)d_ws + xb_bytes)
                               : (unsigned short*)d_ws;
  float* pp = (float*)((char*)wt + 131072);

  hipLaunchKernelGGL(prep_w, dim3(9), dim3(256), 0, stream,
                     W0, W1, W2, B0, G0, Q0, B1, G1, Q1, B2, G2, Q2, W3, wt, pp);
  if (use_xb) {
    hipLaunchKernelGGL(prep_x, dim3(1024), dim3(256), 0, stream, x, xbp, nX / 8);
    hipLaunchKernelGGL(edge_mlp<1>, dim3(blocks), dim3(256), 0, stream,
                       x, ei, B3, wt, pp, xbp, out, nE);
  } else {
    hipLaunchKernelGGL(edge_mlp<0>, dim3(blocks), dim3(256), 0, stream,
                       x, ei, B3, wt, pp, xbp, out, nE);
  }
}

// Round 12
// 169.980 us; speedup vs baseline: 1.1628x; 1.1628x over previous
//
#include <hip/hip_runtime.h>
#include <hip/hip_bf16.h>

// EdgeNetwork R12: verified R6 base + ONE isolated change (scalar exp2).
// R10/R11 post-mortem: pk-epilogue AND 32-edge tile together fail absmax
// (0.074-0.086) while each ingredient alone passes (R6: 32-edge scalar;
// R7/R8b: 16-edge pk). Mechanism unidentified -> retreat to R6 and apply
// only individually-verified changes:
//  - prescale gamma/beta by 2*log2e at prep (passing in R8b),
//  - scalar tanh = 1 - 2*rcp(exp2f(z)+1); exp2f = native v_exp_f32, saves
//    the 2t mul + log2e mul per element vs __expf(2t).
// Everything else byte-identical to R6 (32 edges/wave, K-permuted weights,
// hidden state in regs, params in LDS, (256,3), 8-barrier dbuf schedule).

typedef float f32x4 __attribute__((ext_vector_type(4)));
typedef __bf16 bf16x8 __attribute__((ext_vector_type(8)));
typedef unsigned int u32x4 __attribute__((ext_vector_type(4)));

#define MFMA16(a, b, c) __builtin_amdgcn_mfma_f32_16x16x32_bf16((a), (b), (c), 0, 0, 0)
#define TWO_LOG2E 2.885390081777927f

static __device__ __forceinline__ unsigned short bf16bits(float f) {
  __bf16 h = (__bf16)f;
  return __builtin_bit_cast(unsigned short, h);
}

static __device__ __forceinline__ unsigned pack2(float a, float b) {
  return (unsigned)bf16bits(a) | ((unsigned)bf16bits(b) << 16);
}

// z is pre-scaled by 2*log2e: tanh(y) = 1 - 2/(2^z + 1), z = 2*log2e*y.
static __device__ __forceinline__ float tanh_fast2(float z) {
  return 1.0f - 2.0f * __builtin_amdgcn_rcpf(exp2f(z) + 1.0f);
}

static __device__ __forceinline__ void gload_lds16(const void* g, void* l) {
  __builtin_amdgcn_global_load_lds(
      (const __attribute__((address_space(1))) void*)g,
      (__attribute__((address_space(3))) void*)l, 16, 0, 0);
}

// K-row permutation for layer>=1 weights (within each 32-row block):
// k = blk + g*8 + j  ->  blk + (j>>2)*16 + g*4 + (j&3)
static __device__ __forceinline__ int permk(int k) {
  const int j = k & 7, g = (k >> 3) & 3;
  return (k & ~31) | ((j >> 2) << 4) | (g << 2) | (j & 3);
}

// ---- prep: x (f32) -> xb (bf16) ----
__global__ void prep_x(const float* __restrict__ x,
                       unsigned short* __restrict__ xb, int n8) {
  int gid = blockIdx.x * blockDim.x + threadIdx.x;
  const int stride = gridDim.x * blockDim.x;
  for (int i = gid; i < n8; i += stride) {
    const float4 a = ((const float4*)x)[i * 2];
    const float4 b = ((const float4*)x)[i * 2 + 1];
    u32x4 o;
    o[0] = pack2(a.x, a.y); o[1] = pack2(a.z, a.w);
    o[2] = pack2(b.x, b.y); o[3] = pack2(b.z, b.w);
    ((u32x4*)xb)[i] = o;
  }
}

// ---- prep: weight slabs (swizzled, K-permuted for W1/W2) + param block ----
// pp[1280] = B0, G0*, Q0*, B1, G1*, Q1*, B2, G2*, Q2*, W3; * = x 2*log2e.
__global__ void prep_w(const float* __restrict__ W0, const float* __restrict__ W1,
                       const float* __restrict__ W2,
                       const float* __restrict__ B0, const float* __restrict__ G0,
                       const float* __restrict__ Q0,
                       const float* __restrict__ B1, const float* __restrict__ G1,
                       const float* __restrict__ Q1,
                       const float* __restrict__ B2, const float* __restrict__ G2,
                       const float* __restrict__ Q2,
                       const float* __restrict__ W3,
                       unsigned short* __restrict__ wt, float* __restrict__ pp) {
  const int t = blockIdx.x;
  const int tid = threadIdx.x;
  if (t == 8) {
    for (int i = tid; i < 1280; i += 256) {
      const int a = i >> 7, o = i & 127;
      float v;
      switch (a) {
        case 0: v = B0[o]; break;
        case 1: v = G0[o] * TWO_LOG2E; break;
        case 2: v = Q0[o] * TWO_LOG2E; break;
        case 3: v = B1[o]; break;
        case 4: v = G1[o] * TWO_LOG2E; break;
        case 5: v = Q1[o] * TWO_LOG2E; break;
        case 6: v = B2[o]; break;
        case 7: v = G2[o] * TWO_LOG2E; break;
        case 8: v = Q2[o] * TWO_LOG2E; break;
        default: v = W3[o]; break;
      }
      pp[i] = v;
    }
    return;
  }
  const float* src; int kbase; int perm;
  if (t < 4)      { src = W0; kbase = t * 64;      perm = 0; }
  else if (t < 6) { src = W1; kbase = (t - 4) * 64; perm = 1; }
  else            { src = W2; kbase = (t - 6) * 64; perm = 1; }
  char* base = (char*)wt + t * 16384;
  const int col = tid & 127;
  const int kb  = (tid >> 7) << 1;
  #pragma unroll
  for (int i = 0; i < 16; ++i) {
    const int kl = kb + (i << 2);
    const int k0 = kbase + kl;
    const int c0 = perm ? permk(k0) : k0;  // c(k0+1) == c0+1 (k0 even)
    const float wa = src[c0 * 128 + col];
    const float wb = src[(c0 + 1) * 128 + col];
    const unsigned pk = pack2(wa, wb);
    const int off = ((col * 64 + kl) * 2) ^ ((col & 7) << 4);
    *(unsigned*)(base + off) = pk;
  }
}

#define P_B0 0
#define P_G0 128
#define P_Q0 256
#define P_B1 384
#define P_G1 512
#define P_Q1 640
#define P_B2 768
#define P_G2 896
#define P_Q2 1024
#define P_W3 1152

template <int XB>
__global__ __launch_bounds__(256, 3) void edge_mlp(
    const float* __restrict__ x, const int* __restrict__ ei,
    const float* __restrict__ B3,
    const unsigned short* __restrict__ wt, const float* __restrict__ pp,
    const unsigned short* __restrict__ xb,
    float* __restrict__ out, int nE)
{
  __shared__ __align__(16) char lds[32768 + 5120];
  float* plds = (float*)(lds + 32768);
  const int tid  = threadIdx.x;
  const int lane = tid & 63;
  const int wv   = tid >> 6;
  const int e    = lane & 15;  // edge within tile (N dim)
  const int g    = lane >> 4;  // k-group / accumulator row group

  const int wbase = blockIdx.x * 128 + wv * 32;  // 32 edges per wave
  const int e0 = wbase + e;
  const int e1 = wbase + 16 + e;
  const int ec0 = e0 < nE ? e0 : nE - 1;
  const int ec1 = e1 < nE ? e1 : nE - 1;
  const int ns0 = ei[ec0], ne0 = ei[nE + ec0];
  const int ns1 = ei[ec1], ne1 = ei[nE + ec1];

  auto stageW = [&](int t, int buf) {
    #pragma unroll
    for (int c = 0; c < 4; ++c) {
      const int o = wv * 4096 + c * 1024;
      gload_lds16((const char*)wt + t * 16384 + o + lane * 16,
                  lds + buf * 16384 + o);
    }
  };

  auto loadW = [&](int buf, int m, int kl) -> bf16x8 {
    const int col = m * 16 + e;
    const int off = ((col * 64 + kl) * 2) ^ ((col & 7) << 4);
    return *(const bf16x8*)(lds + buf * 16384 + off);
  };

  auto loadX = [&](int node, int ko) -> bf16x8 {
    if (XB) {
      return *(const bf16x8*)(xb + (size_t)node * 128 + ko);
    } else {
      const float* src = x + (size_t)node * 128 + ko;
      const float4 ua = *(const float4*)(src);
      const float4 ub = *(const float4*)(src + 4);
      bf16x8 a;
      a[0] = (__bf16)ua.x; a[1] = (__bf16)ua.y; a[2] = (__bf16)ua.z; a[3] = (__bf16)ua.w;
      a[4] = (__bf16)ub.x; a[5] = (__bf16)ub.y; a[6] = (__bf16)ub.z; a[7] = (__bf16)ub.w;
      return a;
    }
  };

  f32x4 acc[8][2];

  auto initAcc = [&](int pb) {
    #pragma unroll
    for (int m = 0; m < 8; ++m) {
      const f32x4 bq = *(const f32x4*)(plds + pb + m * 16 + g * 4);
      acc[m][0] = bq; acc[m][1] = bq;
    }
  };

  auto l0step = [&](int u0, int buf) {
    #pragma unroll
    for (int du = 0; du < 2; ++du) {
      const int u = u0 + du;
      const int ko = (u & 3) * 32 + g * 8;
      const bf16x8 xf0 = loadX(u < 4 ? ns0 : ne0, ko);
      const bf16x8 xf1 = loadX(u < 4 ? ns1 : ne1, ko);
      const int kl = du * 32 + g * 8;
      #pragma unroll
      for (int m = 0; m < 8; ++m) {
        const bf16x8 wf = loadW(buf, m, kl);
        acc[m][0] = MFMA16(wf, xf0, acc[m][0]);
        acc[m][1] = MFMA16(wf, xf1, acc[m][1]);
      }
    }
  };

  unsigned p0[2][8], p1[2][8];

  // LN + tanh + pack (scalar, R6 structure; params pre-scaled by 2*log2e).
  auto epi = [&](int pg, int pq) {
    #pragma unroll
    for (int j = 0; j < 2; ++j) {
      float s1 = 0.f, s2 = 0.f;
      #pragma unroll
      for (int m = 0; m < 8; ++m)
        #pragma unroll
        for (int r = 0; r < 4; ++r) {
          const float t = acc[m][j][r];
          s1 += t;
          s2 = __builtin_fmaf(t, t, s2);
        }
      s1 += __shfl_xor(s1, 16); s2 += __shfl_xor(s2, 16);
      s1 += __shfl_xor(s1, 32); s2 += __shfl_xor(s2, 32);
      const float mu  = s1 * 0.0078125f;
      const float inv = __builtin_amdgcn_rsqf(s2 * 0.0078125f - mu * mu + 1e-5f);
      #pragma unroll
      for (int m = 0; m < 8; ++m) {
        const f32x4 gq = *(const f32x4*)(plds + pg + m * 16 + g * 4);
        const f32x4 qq = *(const f32x4*)(plds + pq + m * 16 + g * 4);
        float th[4];
        #pragma unroll
        for (int r = 0; r < 4; ++r) {
          const float z = __builtin_fmaf(acc[m][j][r] - mu, inv * gq[r], qq[r]);
          th[r] = tanh_fast2(z);
        }
        p0[j][m] = pack2(th[0], th[1]);
        p1[j][m] = pack2(th[2], th[3]);
      }
    }
  };

  auto lstep = [&](int u0, int buf) {
    #pragma unroll
    for (int du = 0; du < 2; ++du) {
      const int u = u0 + du;
      const int kl = du * 32 + g * 8;
      u32x4 w0, w1;
      w0[0] = p0[0][2 * u];     w0[1] = p1[0][2 * u];
      w0[2] = p0[0][2 * u + 1]; w0[3] = p1[0][2 * u + 1];
      w1[0] = p0[1][2 * u];     w1[1] = p1[1][2 * u];
      w1[2] = p0[1][2 * u + 1]; w1[3] = p1[1][2 * u + 1];
      const bf16x8 bf0 = __builtin_bit_cast(bf16x8, w0);
      const bf16x8 bf1 = __builtin_bit_cast(bf16x8, w1);
      #pragma unroll
      for (int m = 0; m < 8; ++m) {
        const bf16x8 wf = loadW(buf, m, kl);
        acc[m][0] = MFMA16(wf, bf0, acc[m][0]);
        acc[m][1] = MFMA16(wf, bf1, acc[m][1]);
      }
    }
  };

  // ---------------- schedule (8 barriers, dbuf slabs) ----------------
  stageW(0, 0);
  for (int i = tid; i < 1280; i += 256) plds[i] = pp[i];
  __syncthreads();

  initAcc(P_B0);
  stageW(1, 1); l0step(0, 0); __syncthreads();
  stageW(2, 0); l0step(2, 1); __syncthreads();
  stageW(3, 1); l0step(4, 0); __syncthreads();
  stageW(4, 0); l0step(6, 1); __syncthreads();            // buf0 <- W1 k0-63
  stageW(5, 1);                                            // buf1 <- W1 k64-127
  epi(P_G0, P_Q0); initAcc(P_B1); lstep(0, 0); __syncthreads();
  stageW(6, 0);                                            // buf0 <- W2 k0-63
  lstep(2, 1); __syncthreads();
  stageW(7, 1);                                            // buf1 <- W2 k64-127
  epi(P_G1, P_Q1); initAcc(P_B2); lstep(0, 0); __syncthreads();
  lstep(2, 1);

  // ---- final: LN + tanh + dot W3 + b3 (scalar, exp2 form) ----
  const float b3v = B3[0];
  #pragma unroll
  for (int j = 0; j < 2; ++j) {
    float s1 = 0.f, s2 = 0.f;
    #pragma unroll
    for (int m = 0; m < 8; ++m)
      #pragma unroll
      for (int r = 0; r < 4; ++r) {
        const float t = acc[m][j][r];
        s1 += t;
        s2 = __builtin_fmaf(t, t, s2);
      }
    s1 += __shfl_xor(s1, 16); s2 += __shfl_xor(s2, 16);
    s1 += __shfl_xor(s1, 32); s2 += __shfl_xor(s2, 32);
    const float mu  = s1 * 0.0078125f;
    const float inv = __builtin_amdgcn_rsqf(s2 * 0.0078125f - mu * mu + 1e-5f);
    float d = 0.f;
    #pragma unroll
    for (int m = 0; m < 8; ++m) {
      const f32x4 gq  = *(const f32x4*)(plds + P_G2 + m * 16 + g * 4);
      const f32x4 qq  = *(const f32x4*)(plds + P_Q2 + m * 16 + g * 4);
      const f32x4 w3q = *(const f32x4*)(plds + P_W3 + m * 16 + g * 4);
      #pragma unroll
      for (int r = 0; r < 4; ++r) {
        const float z = __builtin_fmaf(acc[m][j][r] - mu, inv * gq[r], qq[r]);
        d = __builtin_fmaf(tanh_fast2(z), w3q[r], d);
      }
    }
    d += __shfl_xor(d, 16);
    d += __shfl_xor(d, 32);
    const int eid = wbase + j * 16 + e;
    if (g == 0 && eid < nE) out[eid] = d + b3v;
  }
}

extern "C" void kernel_launch(void* const* d_in, const int* in_sizes, int n_in,
                              void* d_out, int out_size, void* d_ws, size_t ws_size,
                              hipStream_t stream) {
  const float* x  = (const float*)d_in[0];
  const int*   ei = (const int*)d_in[1];
  const float* W0 = (const float*)d_in[2];
  const float* B0 = (const float*)d_in[3];
  const float* W1 = (const float*)d_in[4];
  const float* B1 = (const float*)d_in[5];
  const float* W2 = (const float*)d_in[6];
  const float* B2 = (const float*)d_in[7];
  const float* W3 = (const float*)d_in[8];
  const float* B3 = (const float*)d_in[9];
  const float* G0 = (const float*)d_in[10];
  const float* Q0 = (const float*)d_in[11];
  const float* G1 = (const float*)d_in[12];
  const float* Q1 = (const float*)d_in[13];
  const float* G2 = (const float*)d_in[14];
  const float* Q2 = (const float*)d_in[15];
  float* out = (float*)d_out;

  const int nX = in_sizes[0];
  const int nE = in_sizes[1] / 2;
  const int blocks = (nE + 127) / 128;

  const size_t xb_bytes = ((size_t)nX * 2 + 255) & ~(size_t)255;
  const int use_xb = (ws_size >= xb_bytes + 131072 + 5120) ? 1 : 0;

  unsigned short* xbp = (unsigned short*)d_ws;
  unsigned short* wt  = use_xb ? (unsigned short*)((char*)d_ws + xb_bytes)
                               : (unsigned short*)d_ws;
  float* pp = (float*)((char*)wt + 131072);

  hipLaunchKernelGGL(prep_w, dim3(9), dim3(256), 0, stream,
                     W0, W1, W2, B0, G0, Q0, B1, G1, Q1, B2, G2, Q2, W3, wt, pp);
  if (use_xb) {
    hipLaunchKernelGGL(prep_x, dim3(1024), dim3(256), 0, stream, x, xbp, nX / 8);
    hipLaunchKernelGGL(edge_mlp<1>, dim3(blocks), dim3(256), 0, stream,
                       x, ei, B3, wt, pp, xbp, out, nE);
  } else {
    hipLaunchKernelGGL(edge_mlp<0>, dim3(blocks), dim3(256), 0, stream,
                       x, ei, B3, wt, pp, xbp, out, nE);
  }
}

// Round 13
// 149.831 us; speedup vs baseline: 1.3192x; 1.1345x over previous
//
#include <hip/hip_runtime.h>
#include <hip/hip_bf16.h>

// EdgeNetwork R13: R12 (verified scalar 32-edge + prescaled params) with two
// epilogue VALU trims:
//  1. raw v_exp_f32 via __builtin_amdgcn_exp2f (R12's OCML exp2f carries a
//     denormal-fixup sequence, VALUBusy 67->73.6%, dur +9us vs __expf).
//     Flush at extreme z is harmless: tanh saturates to +-1 exactly.
//  2. normalize-then-affine: an = fma(a, inv, -mu*inv); z = fma(an, g', q')
//     (saves 1 op/channel-instance; -mu*inv hoisted per edge-half).
// Attribution note: pk-epilogue AND 32-edge is the broken combo (R10/R11);
// scalar exp2 forms are verified (R8b 16-edge asm, R12 32-edge OCML).

typedef float f32x4 __attribute__((ext_vector_type(4)));
typedef __bf16 bf16x8 __attribute__((ext_vector_type(8)));
typedef unsigned int u32x4 __attribute__((ext_vector_type(4)));

#define MFMA16(a, b, c) __builtin_amdgcn_mfma_f32_16x16x32_bf16((a), (b), (c), 0, 0, 0)
#define TWO_LOG2E 2.885390081777927f

static __device__ __forceinline__ unsigned short bf16bits(float f) {
  __bf16 h = (__bf16)f;
  return __builtin_bit_cast(unsigned short, h);
}

static __device__ __forceinline__ unsigned pack2(float a, float b) {
  return (unsigned)bf16bits(a) | ((unsigned)bf16bits(b) << 16);
}

// z pre-scaled by 2*log2e: tanh(y) = 1 - 2/(2^z + 1).
static __device__ __forceinline__ float tanh_fast2(float z) {
#if __has_builtin(__builtin_amdgcn_exp2f)
  const float ex = __builtin_amdgcn_exp2f(z);  // bare v_exp_f32
#else
  const float ex = exp2f(z);
#endif
  return 1.0f - 2.0f * __builtin_amdgcn_rcpf(ex + 1.0f);
}

static __device__ __forceinline__ void gload_lds16(const void* g, void* l) {
  __builtin_amdgcn_global_load_lds(
      (const __attribute__((address_space(1))) void*)g,
      (__attribute__((address_space(3))) void*)l, 16, 0, 0);
}

// K-row permutation for layer>=1 weights (within each 32-row block):
// k = blk + g*8 + j  ->  blk + (j>>2)*16 + g*4 + (j&3)
static __device__ __forceinline__ int permk(int k) {
  const int j = k & 7, g = (k >> 3) & 3;
  return (k & ~31) | ((j >> 2) << 4) | (g << 2) | (j & 3);
}

// ---- prep: x (f32) -> xb (bf16) ----
__global__ void prep_x(const float* __restrict__ x,
                       unsigned short* __restrict__ xb, int n8) {
  int gid = blockIdx.x * blockDim.x + threadIdx.x;
  const int stride = gridDim.x * blockDim.x;
  for (int i = gid; i < n8; i += stride) {
    const float4 a = ((const float4*)x)[i * 2];
    const float4 b = ((const float4*)x)[i * 2 + 1];
    u32x4 o;
    o[0] = pack2(a.x, a.y); o[1] = pack2(a.z, a.w);
    o[2] = pack2(b.x, b.y); o[3] = pack2(b.z, b.w);
    ((u32x4*)xb)[i] = o;
  }
}

// ---- prep: weight slabs (swizzled, K-permuted for W1/W2) + param block ----
// pp[1280] = B0, G0*, Q0*, B1, G1*, Q1*, B2, G2*, Q2*, W3; * = x 2*log2e.
__global__ void prep_w(const float* __restrict__ W0, const float* __restrict__ W1,
                       const float* __restrict__ W2,
                       const float* __restrict__ B0, const float* __restrict__ G0,
                       const float* __restrict__ Q0,
                       const float* __restrict__ B1, const float* __restrict__ G1,
                       const float* __restrict__ Q1,
                       const float* __restrict__ B2, const float* __restrict__ G2,
                       const float* __restrict__ Q2,
                       const float* __restrict__ W3,
                       unsigned short* __restrict__ wt, float* __restrict__ pp) {
  const int t = blockIdx.x;
  const int tid = threadIdx.x;
  if (t == 8) {
    for (int i = tid; i < 1280; i += 256) {
      const int a = i >> 7, o = i & 127;
      float v;
      switch (a) {
        case 0: v = B0[o]; break;
        case 1: v = G0[o] * TWO_LOG2E; break;
        case 2: v = Q0[o] * TWO_LOG2E; break;
        case 3: v = B1[o]; break;
        case 4: v = G1[o] * TWO_LOG2E; break;
        case 5: v = Q1[o] * TWO_LOG2E; break;
        case 6: v = B2[o]; break;
        case 7: v = G2[o] * TWO_LOG2E; break;
        case 8: v = Q2[o] * TWO_LOG2E; break;
        default: v = W3[o]; break;
      }
      pp[i] = v;
    }
    return;
  }
  const float* src; int kbase; int perm;
  if (t < 4)      { src = W0; kbase = t * 64;      perm = 0; }
  else if (t < 6) { src = W1; kbase = (t - 4) * 64; perm = 1; }
  else            { src = W2; kbase = (t - 6) * 64; perm = 1; }
  char* base = (char*)wt + t * 16384;
  const int col = tid & 127;
  const int kb  = (tid >> 7) << 1;
  #pragma unroll
  for (int i = 0; i < 16; ++i) {
    const int kl = kb + (i << 2);
    const int k0 = kbase + kl;
    const int c0 = perm ? permk(k0) : k0;  // c(k0+1) == c0+1 (k0 even)
    const float wa = src[c0 * 128 + col];
    const float wb = src[(c0 + 1) * 128 + col];
    const unsigned pk = pack2(wa, wb);
    const int off = ((col * 64 + kl) * 2) ^ ((col & 7) << 4);
    *(unsigned*)(base + off) = pk;
  }
}

#define P_B0 0
#define P_G0 128
#define P_Q0 256
#define P_B1 384
#define P_G1 512
#define P_Q1 640
#define P_B2 768
#define P_G2 896
#define P_Q2 1024
#define P_W3 1152

template <int XB>
__global__ __launch_bounds__(256, 3) void edge_mlp(
    const float* __restrict__ x, const int* __restrict__ ei,
    const float* __restrict__ B3,
    const unsigned short* __restrict__ wt, const float* __restrict__ pp,
    const unsigned short* __restrict__ xb,
    float* __restrict__ out, int nE)
{
  __shared__ __align__(16) char lds[32768 + 5120];
  float* plds = (float*)(lds + 32768);
  const int tid  = threadIdx.x;
  const int lane = tid & 63;
  const int wv   = tid >> 6;
  const int e    = lane & 15;  // edge within tile (N dim)
  const int g    = lane >> 4;  // k-group / accumulator row group

  const int wbase = blockIdx.x * 128 + wv * 32;  // 32 edges per wave
  const int e0 = wbase + e;
  const int e1 = wbase + 16 + e;
  const int ec0 = e0 < nE ? e0 : nE - 1;
  const int ec1 = e1 < nE ? e1 : nE - 1;
  const int ns0 = ei[ec0], ne0 = ei[nE + ec0];
  const int ns1 = ei[ec1], ne1 = ei[nE + ec1];

  auto stageW = [&](int t, int buf) {
    #pragma unroll
    for (int c = 0; c < 4; ++c) {
      const int o = wv * 4096 + c * 1024;
      gload_lds16((const char*)wt + t * 16384 + o + lane * 16,
                  lds + buf * 16384 + o);
    }
  };

  auto loadW = [&](int buf, int m, int kl) -> bf16x8 {
    const int col = m * 16 + e;
    const int off = ((col * 64 + kl) * 2) ^ ((col & 7) << 4);
    return *(const bf16x8*)(lds + buf * 16384 + off);
  };

  auto loadX = [&](int node, int ko) -> bf16x8 {
    if (XB) {
      return *(const bf16x8*)(xb + (size_t)node * 128 + ko);
    } else {
      const float* src = x + (size_t)node * 128 + ko;
      const float4 ua = *(const float4*)(src);
      const float4 ub = *(const float4*)(src + 4);
      bf16x8 a;
      a[0] = (__bf16)ua.x; a[1] = (__bf16)ua.y; a[2] = (__bf16)ua.z; a[3] = (__bf16)ua.w;
      a[4] = (__bf16)ub.x; a[5] = (__bf16)ub.y; a[6] = (__bf16)ub.z; a[7] = (__bf16)ub.w;
      return a;
    }
  };

  f32x4 acc[8][2];

  auto initAcc = [&](int pb) {
    #pragma unroll
    for (int m = 0; m < 8; ++m) {
      const f32x4 bq = *(const f32x4*)(plds + pb + m * 16 + g * 4);
      acc[m][0] = bq; acc[m][1] = bq;
    }
  };

  auto l0step = [&](int u0, int buf) {
    #pragma unroll
    for (int du = 0; du < 2; ++du) {
      const int u = u0 + du;
      const int ko = (u & 3) * 32 + g * 8;
      const bf16x8 xf0 = loadX(u < 4 ? ns0 : ne0, ko);
      const bf16x8 xf1 = loadX(u < 4 ? ns1 : ne1, ko);
      const int kl = du * 32 + g * 8;
      #pragma unroll
      for (int m = 0; m < 8; ++m) {
        const bf16x8 wf = loadW(buf, m, kl);
        acc[m][0] = MFMA16(wf, xf0, acc[m][0]);
        acc[m][1] = MFMA16(wf, xf1, acc[m][1]);
      }
    }
  };

  unsigned p0[2][8], p1[2][8];

  // LN + tanh + pack (scalar; params pre-scaled by 2*log2e).
  // normalize-then-affine: an = fma(a, inv, nm); z = fma(an, g', q').
  auto epi = [&](int pg, int pq) {
    #pragma unroll
    for (int j = 0; j < 2; ++j) {
      float s1 = 0.f, s2 = 0.f;
      #pragma unroll
      for (int m = 0; m < 8; ++m)
        #pragma unroll
        for (int r = 0; r < 4; ++r) {
          const float t = acc[m][j][r];
          s1 += t;
          s2 = __builtin_fmaf(t, t, s2);
        }
      s1 += __shfl_xor(s1, 16); s2 += __shfl_xor(s2, 16);
      s1 += __shfl_xor(s1, 32); s2 += __shfl_xor(s2, 32);
      const float mu  = s1 * 0.0078125f;
      const float inv = __builtin_amdgcn_rsqf(s2 * 0.0078125f - mu * mu + 1e-5f);
      const float nm  = -mu * inv;
      #pragma unroll
      for (int m = 0; m < 8; ++m) {
        const f32x4 gq = *(const f32x4*)(plds + pg + m * 16 + g * 4);
        const f32x4 qq = *(const f32x4*)(plds + pq + m * 16 + g * 4);
        float th[4];
        #pragma unroll
        for (int r = 0; r < 4; ++r) {
          const float an = __builtin_fmaf(acc[m][j][r], inv, nm);
          const float z  = __builtin_fmaf(an, gq[r], qq[r]);
          th[r] = tanh_fast2(z);
        }
        p0[j][m] = pack2(th[0], th[1]);
        p1[j][m] = pack2(th[2], th[3]);
      }
    }
  };

  auto lstep = [&](int u0, int buf) {
    #pragma unroll
    for (int du = 0; du < 2; ++du) {
      const int u = u0 + du;
      const int kl = du * 32 + g * 8;
      u32x4 w0, w1;
      w0[0] = p0[0][2 * u];     w0[1] = p1[0][2 * u];
      w0[2] = p0[0][2 * u + 1]; w0[3] = p1[0][2 * u + 1];
      w1[0] = p0[1][2 * u];     w1[1] = p1[1][2 * u];
      w1[2] = p0[1][2 * u + 1]; w1[3] = p1[1][2 * u + 1];
      const bf16x8 bf0 = __builtin_bit_cast(bf16x8, w0);
      const bf16x8 bf1 = __builtin_bit_cast(bf16x8, w1);
      #pragma unroll
      for (int m = 0; m < 8; ++m) {
        const bf16x8 wf = loadW(buf, m, kl);
        acc[m][0] = MFMA16(wf, bf0, acc[m][0]);
        acc[m][1] = MFMA16(wf, bf1, acc[m][1]);
      }
    }
  };

  // ---------------- schedule (8 barriers, dbuf slabs) ----------------
  stageW(0, 0);
  for (int i = tid; i < 1280; i += 256) plds[i] = pp[i];
  __syncthreads();

  initAcc(P_B0);
  stageW(1, 1); l0step(0, 0); __syncthreads();
  stageW(2, 0); l0step(2, 1); __syncthreads();
  stageW(3, 1); l0step(4, 0); __syncthreads();
  stageW(4, 0); l0step(6, 1); __syncthreads();            // buf0 <- W1 k0-63
  stageW(5, 1);                                            // buf1 <- W1 k64-127
  epi(P_G0, P_Q0); initAcc(P_B1); lstep(0, 0); __syncthreads();
  stageW(6, 0);                                            // buf0 <- W2 k0-63
  lstep(2, 1); __syncthreads();
  stageW(7, 1);                                            // buf1 <- W2 k64-127
  epi(P_G1, P_Q1); initAcc(P_B2); lstep(0, 0); __syncthreads();
  lstep(2, 1);

  // ---- final: LN + tanh + dot W3 + b3 (scalar, exp2 form) ----
  const float b3v = B3[0];
  #pragma unroll
  for (int j = 0; j < 2; ++j) {
    float s1 = 0.f, s2 = 0.f;
    #pragma unroll
    for (int m = 0; m < 8; ++m)
      #pragma unroll
      for (int r = 0; r < 4; ++r) {
        const float t = acc[m][j][r];
        s1 += t;
        s2 = __builtin_fmaf(t, t, s2);
      }
    s1 += __shfl_xor(s1, 16); s2 += __shfl_xor(s2, 16);
    s1 += __shfl_xor(s1, 32); s2 += __shfl_xor(s2, 32);
    const float mu  = s1 * 0.0078125f;
    const float inv = __builtin_amdgcn_rsqf(s2 * 0.0078125f - mu * mu + 1e-5f);
    const float nm  = -mu * inv;
    float d = 0.f;
    #pragma unroll
    for (int m = 0; m < 8; ++m) {
      const f32x4 gq  = *(const f32x4*)(plds + P_G2 + m * 16 + g * 4);
      const f32x4 qq  = *(const f32x4*)(plds + P_Q2 + m * 16 + g * 4);
      const f32x4 w3q = *(const f32x4*)(plds + P_W3 + m * 16 + g * 4);
      #pragma unroll
      for (int r = 0; r < 4; ++r) {
        const float an = __builtin_fmaf(acc[m][j][r], inv, nm);
        const float z  = __builtin_fmaf(an, gq[r], qq[r]);
        d = __builtin_fmaf(tanh_fast2(z), w3q[r], d);
      }
    }
    d += __shfl_xor(d, 16);
    d += __shfl_xor(d, 32);
    const int eid = wbase + j * 16 + e;
    if (g == 0 && eid < nE) out[eid] = d + b3v;
  }
}

extern "C" void kernel_launch(void* const* d_in, const int* in_sizes, int n_in,
                              void* d_out, int out_size, void* d_ws, size_t ws_size,
                              hipStream_t stream) {
  const float* x  = (const float*)d_in[0];
  const int*   ei = (const int*)d_in[1];
  const float* W0 = (const float*)d_in[2];
  const float* B0 = (const float*)d_in[3];
  const float* W1 = (const float*)d_in[4];
  const float* B1 = (const float*)d_in[5];
  const float* W2 = (const float*)d_in[6];
  const float* B2 = (const float*)d_in[7];
  const float* W3 = (const float*)d_in[8];
  const float* B3 = (const float*)d_in[9];
  const float* G0 = (const float*)d_in[10];
  const float* Q0 = (const float*)d_in[11];
  const float* G1 = (const float*)d_in[12];
  const float* Q1 = (const float*)d_in[13];
  const float* G2 = (const float*)d_in[14];
  const float* Q2 = (const float*)d_in[15];
  float* out = (float*)d_out;

  const int nX = in_sizes[0];
  const int nE = in_sizes[1] / 2;
  const int blocks = (nE + 127) / 128;

  const size_t xb_bytes = ((size_t)nX * 2 + 255) & ~(size_t)255;
  const int use_xb = (ws_size >= xb_bytes + 131072 + 5120) ? 1 : 0;

  unsigned short* xbp = (unsigned short*)d_ws;
  unsigned short* wt  = use_xb ? (unsigned short*)((char*)d_ws + xb_bytes)
                               : (unsigned short*)d_ws;
  float* pp = (float*)((char*)wt + 131072);

  hipLaunchKernelGGL(prep_w, dim3(9), dim3(256), 0, stream,
                     W0, W1, W2, B0, G0, Q0, B1, G1, Q1, B2, G2, Q2, W3, wt, pp);
  if (use_xb) {
    hipLaunchKernelGGL(prep_x, dim3(1024), dim3(256), 0, stream, x, xbp, nX / 8);
    hipLaunchKernelGGL(edge_mlp<1>, dim3(blocks), dim3(256), 0, stream,
                       x, ei, B3, wt, pp, xbp, out, nE);
  } else {
    hipLaunchKernelGGL(edge_mlp<0>, dim3(blocks), dim3(256), 0, stream,
                       x, ei, B3, wt, pp, xbp, out, nE);
  }
}